// Round 3
// baseline (459.517 us; speedup 1.0000x reference)
//
#include <hip/hip_runtime.h>

// TreeLRU: B=16, N=4095 heap, IN=OUT=512, S=256.
// Round 7: GEMM rebuilt as depth-3 counted-vmcnt pipeline (T3+T4):
// BK=32, 4 LDS buffers (64KB total, 2 blocks/CU), fully unrolled 16-tile
// K-loop. Per iter: vmcnt(8) [tiles i+1,i+2 stay in flight] -> raw
// s_barrier -> STAGE(i+3) -> setprio+16 MFMA. vmcnt never drains to 0 in
// the main loop (m218: counted-vs-drain0 = +38-73%). LDS slot swizzle
// (row>>3)*32+(kc<<3)+(row&7): conflict-free ds_read_b128 with a LINEAR
// global_load_lds destination (source-side permutation, lesson #21).
// prep_all / tree_up2 unchanged from round 6 for attribution.

#define ROWS 65520
#define KDIM 512

typedef __attribute__((ext_vector_type(8))) short bf16x8;
typedef __attribute__((ext_vector_type(4))) float f32x4;

__device__ __forceinline__ unsigned short f2bf(float f) {
    unsigned int u = __float_as_uint(f);
    unsigned int r = (u + 0x7FFFu + ((u >> 16) & 1u)) >> 16;
    return (unsigned short)r;
}
__device__ __forceinline__ float b2f(unsigned short h) {
    return __uint_as_float(((unsigned int)h) << 16);
}
__device__ __forceinline__ float b2f_lo(unsigned int p) {      // low bf16 of pair
    return __uint_as_float(p << 16);
}
__device__ __forceinline__ float b2f_hi(unsigned int p) {      // high bf16 of pair
    return __uint_as_float(p & 0xFFFF0000u);
}

// ---------------- merged prep: prep_M | prep_C | prep_bias | cvt ----------------
#define PC_BASE   1024
#define PB_BASE   2048
#define CVT_BASE  2176
#define CVT_BLKS  2048
#define PREP_GRID 4224
#define CVT_N4    8386560          // ROWS*512/4

__global__ __launch_bounds__(256) void prep_all(const float* __restrict__ x,
                                                unsigned short* __restrict__ x16,
                                                const float* __restrict__ W,
                                                const float* __restrict__ Bre,
                                                const float* __restrict__ Bim,
                                                const float* __restrict__ gamma_log,
                                                unsigned short* __restrict__ M16,
                                                const float* __restrict__ bin,
                                                float* __restrict__ biasc,
                                                const float* __restrict__ Cre,
                                                const float* __restrict__ Cim,
                                                unsigned short* __restrict__ C16) {
    __shared__ float Bs[16][17];
    __shared__ float Ws[16][17];
    const int blk = blockIdx.x;
    const int t = threadIdx.x;

    if (blk < PC_BASE) {
        // ---- prep_M: 32x32 grid of 16x16 tiles ----
        const int bx = blk & 31;       // j tile
        const int by = blk >> 5;       // cc tile
        const int tx = t & 15;
        const int ty = t >> 4;
        const int j  = bx * 16 + tx;
        const int cc = by * 16 + ty;
        const float* Bsel = (cc < 256) ? (Bre + (size_t)cc * 512)
                                       : (Bim + (size_t)(cc - 256) * 512);
        float acc = 0.f;
        for (int kt = 0; kt < 512; kt += 16) {
            Bs[ty][tx] = Bsel[kt + tx];
            Ws[ty][tx] = W[(size_t)(kt + ty) * 512 + j];
            __syncthreads();
#pragma unroll
            for (int k = 0; k < 16; ++k) acc += Bs[ty][k] * Ws[k][tx];
            __syncthreads();
        }
        float g = expf(gamma_log[cc & 255]);
        M16[(size_t)cc * 512 + j] = f2bf(acc * g);
    } else if (blk < PB_BASE) {
        // ---- prep_C ----
        int idx = (blk - PC_BASE) * 256 + t;   // 0..262143
        int o = idx >> 9;
        int s = idx & 511;
        float v = (s < 256) ? Cre[(size_t)o * 256 + s] : -Cim[(size_t)o * 256 + (s - 256)];
        C16[idx] = f2bf(v);
    } else if (blk < CVT_BASE) {
        // ---- prep_bias: 4 channels per block, one wave each ----
        const int c = (blk - PB_BASE) * 4 + (t >> 6);   // 0..511
        const int lane = t & 63;
        const float* Bsel = (c < 256) ? (Bre + (size_t)c * 512)
                                      : (Bim + (size_t)(c - 256) * 512);
        float acc = 0.f;
#pragma unroll
        for (int i = lane; i < 512; i += 64) acc += bin[i] * Bsel[i];
#pragma unroll
        for (int off = 32; off > 0; off >>= 1) acc += __shfl_down(acc, off, 64);
        if (lane == 0) biasc[c] = acc * expf(gamma_log[c & 255]);
    } else {
        // ---- cvt f32 -> bf16, grid-stride: 16 float4 per thread ----
        int i = (blk - CVT_BASE) * 256 + t;
#pragma unroll 4
        for (; i < CVT_N4; i += CVT_BLKS * 256) {
            float4 v = ((const float4*)x)[i];
            ushort4 o;
            o.x = f2bf(v.x); o.y = f2bf(v.y); o.z = f2bf(v.z); o.w = f2bf(v.w);
            ((ushort4*)x16)[i] = o;
        }
    }
}

// ---------------- bf16 MFMA GEMM: C = A @ B^T (+bias), K=N=512 ----------------
// 128x128 block tile, 4 waves, each wave 64x64 (4x4 of 16x16x32 MFMA).
// BK=32, 16 K-tiles, 4 LDS buffers, depth-3 counted-vmcnt pipeline.
// LDS slot for logical (row, kc16B): slot = (row>>3)*32 + (kc<<3) + (row&7)
//   -> ds_read_b128 bank = (row&7)*4: 8 rows tile all 32 banks, 2-way = free.
//   global_load_lds dest stays LINEAR in slot; source address carries the
//   inverse permutation: row(s) = (s>>5)*8 + (s&7), kc(s) = (s>>3)&3.
template <bool OUT_BF16>
__global__ __launch_bounds__(256) void gemm_mfma(const unsigned short* __restrict__ A,
                                                 const unsigned short* __restrict__ Bm,
                                                 const float* __restrict__ bias,
                                                 void* __restrict__ Cout,
                                                 int Mrows) {
    __shared__ __align__(16) unsigned short As[4 * 4096];   // 4 bufs x 8KB
    __shared__ __align__(16) unsigned short Bs[4 * 4096];
    const int t = threadIdx.x;
    const int lane = t & 63;
    const int w = t >> 6;
    const int wr = (w >> 1) * 64;
    const int wc = (w & 1) * 64;
    const int bid = blockIdx.x;
    const int xcd = bid & 7;
    const int lid = bid >> 3;               // 0..255
    const int rowblk = xcd * 64 + (lid >> 2);
    const int colblk = lid & 3;
    const int row0 = rowblk * 128;
    const int col0 = colblk * 128;

    f32x4 acc[4][4] = {};

    // per-thread stage sources: slots t and t+256 (A and B each)
    const unsigned short* gaB[2];
    const unsigned short* gbB[2];
    int sl[2];
#pragma unroll
    for (int q = 0; q < 2; ++q) {
        const int s   = q * 256 + t;             // physical LDS slot 0..511
        const int row = ((s >> 5) << 3) + (s & 7);
        const int kc  = (s >> 3) & 3;
        int ar = row0 + row; if (ar >= Mrows) ar = Mrows - 1;
        gaB[q] = A + (size_t)ar * KDIM + kc * 8;
        gbB[q] = Bm + (size_t)(col0 + row) * KDIM + kc * 8;
        sl[q] = s;
    }

    // per-thread ds_read slot bases (fragment i/j adds i*64)
    const int l15 = lane & 15;
    const int aslot = ((wr >> 3) + (l15 >> 3)) * 32 + ((lane >> 4) << 3) + (lane & 7);
    const int bslot = ((wc >> 3) + (l15 >> 3)) * 32 + ((lane >> 4) << 3) + (lane & 7);

#define STAGE(PB, IT)                                                          \
    do {                                                                       \
        _Pragma("unroll")                                                      \
        for (int q = 0; q < 2; ++q) {                                          \
            __builtin_amdgcn_global_load_lds(                                  \
                (const __attribute__((address_space(1))) unsigned int*)(gaB[q] + (IT) * 32), \
                (__attribute__((address_space(3))) unsigned int*)(As + (PB) * 4096 + sl[q] * 8), \
                16, 0, 0);                                                     \
            __builtin_amdgcn_global_load_lds(                                  \
                (const __attribute__((address_space(1))) unsigned int*)(gbB[q] + (IT) * 32), \
                (__attribute__((address_space(3))) unsigned int*)(Bs + (PB) * 4096 + sl[q] * 8), \
                16, 0, 0);                                                     \
        }                                                                      \
    } while (0)

#define COMPUTE(PB)                                                            \
    do {                                                                       \
        bf16x8 af[4], bfr[4];                                                  \
        _Pragma("unroll")                                                      \
        for (int i = 0; i < 4; ++i)                                            \
            af[i] = *(const bf16x8*)(As + (PB) * 4096 + (aslot + i * 64) * 8); \
        _Pragma("unroll")                                                      \
        for (int j = 0; j < 4; ++j)                                            \
            bfr[j] = *(const bf16x8*)(Bs + (PB) * 4096 + (bslot + j * 64) * 8);\
        _Pragma("unroll")                                                      \
        for (int i = 0; i < 4; ++i)                                            \
            _Pragma("unroll")                                                  \
            for (int j = 0; j < 4; ++j)                                        \
                acc[i][j] = __builtin_amdgcn_mfma_f32_16x16x32_bf16(           \
                    af[i], bfr[j], acc[i][j], 0, 0, 0);                        \
    } while (0)

    // iter i: wait tile i (counted: i+1,i+2 stay in flight), barrier,
    // stage tile i+3 into buf (i+3)&3 (= buffer computed at iter i-1,
    // barrier-protected), compute tile i.
#define PIPE_ITER(IT, WAITN, DOSTAGE)                                          \
    do {                                                                       \
        asm volatile("s_waitcnt vmcnt(" #WAITN ")" ::: "memory");              \
        __builtin_amdgcn_s_barrier();                                          \
        if (DOSTAGE) STAGE((IT + 3) & 3, IT + 3);                              \
        __builtin_amdgcn_s_setprio(1);                                         \
        COMPUTE((IT) & 3);                                                     \
        __builtin_amdgcn_s_setprio(0);                                         \
    } while (0)

    STAGE(0, 0);
    STAGE(1, 1);
    STAGE(2, 2);            // 12 vmem in flight; no drain

    PIPE_ITER(0, 8, true);
    PIPE_ITER(1, 8, true);
    PIPE_ITER(2, 8, true);
    PIPE_ITER(3, 8, true);
    PIPE_ITER(4, 8, true);
    PIPE_ITER(5, 8, true);
    PIPE_ITER(6, 8, true);
    PIPE_ITER(7, 8, true);
    PIPE_ITER(8, 8, true);
    PIPE_ITER(9, 8, true);
    PIPE_ITER(10, 8, true);
    PIPE_ITER(11, 8, true);
    PIPE_ITER(12, 8, true);
    PIPE_ITER(13, 8, false);
    PIPE_ITER(14, 4, false);
    PIPE_ITER(15, 0, false);

#undef PIPE_ITER
#undef COMPUTE
#undef STAGE

    // epilogue: C/D layout col=lane&15, row=(lane>>4)*4+reg  [m89/m91 verified]
    const int cq = lane >> 4;
    const int cl = lane & 15;
#pragma unroll
    for (int i = 0; i < 4; ++i) {
#pragma unroll
        for (int j = 0; j < 4; ++j) {
#pragma unroll
            for (int r = 0; r < 4; ++r) {
                int grow = row0 + wr + i * 16 + cq * 4 + r;
                int gcol = col0 + wc + j * 16 + cl;
                if (grow < Mrows) {
                    float v = acc[i][j][r];
                    if (bias) v += bias[gcol];
                    if (OUT_BF16)
                        ((unsigned short*)Cout)[(size_t)grow * 512 + gcol] = f2bf(v);
                    else
                        ((float*)Cout)[(size_t)grow * 512 + gcol] = v;
                }
            }
        }
    }
}

// ---------------- tree recurrence, v2 (unchanged from round 6) ----------------
template <int E>
__global__ __launch_bounds__(256) void tree_up2(unsigned short* __restrict__ buf,
                                                const float* __restrict__ nu_log,
                                                const float* __restrict__ theta_log,
                                                int root_base, int nroots) {
    const int b = blockIdx.x;
    const int h = threadIdx.x >> 7;
    const int j2 = (threadIdx.x & 127) * 2;        // channel pair base
    const int rr = blockIdx.y * 2 + h;
    if (rr >= nroots) return;
    const int rs = root_base + rr;
    constexpr int LEAVES = 1 << E;
    constexpr int NODES = LEAVES - 1;

    float lr0, li0, lr1, li1;
    { const float lam = expf(-expf(nu_log[j2]));     const float th = expf(theta_log[j2]);
      lr0 = lam * cosf(th); li0 = lam * sinf(th); }
    { const float lam = expf(-expf(nu_log[j2 + 1])); const float th = expf(theta_log[j2 + 1]);
      lr1 = lam * cosf(th); li1 = lam * sinf(th); }
    const size_t base = (size_t)b * 4095;

    // 1) issue ALL loads (62 x 4B per thread, independent) ...
    unsigned int pr[LEAVES], pi[LEAVES];
    const int nbL = ((rs + 1) << E) - 1;
#pragma unroll
    for (int i = 0; i < LEAVES; ++i) {
        const size_t r = (base + nbL + i) * 512;
        pr[i] = *(const unsigned int*)(buf + r + j2);
        pi[i] = *(const unsigned int*)(buf + r + 256 + j2);
    }
    unsigned int qr[NODES], qi[NODES];
#pragma unroll
    for (int e = E - 1; e >= 0; --e) {
#pragma unroll
        for (int i = 0; i < (1 << e); ++i) {
            const int idx = LEAVES - (2 << e) + i;
            const size_t r = (base + (((rs + 1) << e) - 1) + i) * 512;
            qr[idx] = *(const unsigned int*)(buf + r + j2);
            qi[idx] = *(const unsigned int*)(buf + r + 256 + j2);
        }
    }
    // ... 2) and only then start consuming (pins MLP; prevents load sinking)
    __builtin_amdgcn_sched_barrier(0);

    float vr0[LEAVES], vi0[LEAVES], vr1[LEAVES], vi1[LEAVES];
#pragma unroll
    for (int i = 0; i < LEAVES; ++i) {
        vr0[i] = b2f_lo(pr[i]); vr1[i] = b2f_hi(pr[i]);
        vi0[i] = b2f_lo(pi[i]); vi1[i] = b2f_hi(pi[i]);
    }
#pragma unroll
    for (int e = E - 1; e >= 0; --e) {
#pragma unroll
        for (int i = 0; i < (1 << e); ++i) {
            const int idx = LEAVES - (2 << e) + i;
            const float cr0 = vr0[2 * i] + vr0[2 * i + 1];
            const float ci0 = vi0[2 * i] + vi0[2 * i + 1];
            const float cr1 = vr1[2 * i] + vr1[2 * i + 1];
            const float ci1 = vi1[2 * i] + vi1[2 * i + 1];
            const float hr0 = lr0 * cr0 - li0 * ci0 + b2f_lo(qr[idx]);
            const float hi0 = lr0 * ci0 + li0 * cr0 + b2f_lo(qi[idx]);
            const float hr1 = lr1 * cr1 - li1 * ci1 + b2f_hi(qr[idx]);
            const float hi1 = lr1 * ci1 + li1 * cr1 + b2f_hi(qi[idx]);
            const size_t r = (base + (((rs + 1) << e) - 1) + i) * 512;
            *(unsigned int*)(buf + r + j2) =
                (unsigned int)f2bf(hr0) | ((unsigned int)f2bf(hr1) << 16);
            *(unsigned int*)(buf + r + 256 + j2) =
                (unsigned int)f2bf(hi0) | ((unsigned int)f2bf(hi1) << 16);
            vr0[i] = hr0; vi0[i] = hi0; vr1[i] = hr1; vi1[i] = hi1;
        }
    }
}

extern "C" void kernel_launch(void* const* d_in, const int* in_sizes, int n_in,
                              void* d_out, int out_size, void* d_ws, size_t ws_size,
                              hipStream_t stream) {
    const float* x         = (const float*)d_in[0];
    const float* W_in      = (const float*)d_in[2];
    const float* b_in      = (const float*)d_in[3];
    const float* nu_log    = (const float*)d_in[4];
    const float* theta_log = (const float*)d_in[5];
    const float* gamma_log = (const float*)d_in[6];
    const float* B_re      = (const float*)d_in[7];
    const float* B_im      = (const float*)d_in[8];
    const float* C_re      = (const float*)d_in[9];
    const float* C_im      = (const float*)d_in[10];
    float* out = (float*)d_out;

    char* ws = (char*)d_ws;
    const size_t HB = (size_t)ROWS * 512 * 2;   // 67,092,480 bytes
    unsigned short* x16   = (unsigned short*)ws;
    unsigned short* hb16  = (unsigned short*)(ws + HB);
    unsigned short* M16   = (unsigned short*)(ws + 2 * HB);
    unsigned short* C16   = (unsigned short*)(ws + 2 * HB + 512 * 512 * 2);
    float*          biasc = (float*)(ws + 2 * HB + 2 * 512 * 512 * 2);

    prep_all<<<PREP_GRID, 256, 0, stream>>>(x, x16, W_in, B_re, B_im, gamma_log,
                                            M16, b_in, biasc, C_re, C_im, C16);

    gemm_mfma<true><<<2048, 256, 0, stream>>>(x16, M16, biasc, hb16, ROWS);

    // levels 10..7 (roots at level 7: nodes 127..254), then 6..3 (roots at
    // level 3: nodes 7..14), then 2..0 (root 0).
    tree_up2<4><<<dim3(16, 64), 256, 0, stream>>>(hb16, nu_log, theta_log, 127, 128);
    tree_up2<4><<<dim3(16, 4),  256, 0, stream>>>(hb16, nu_log, theta_log, 7, 8);
    tree_up2<3><<<dim3(16, 1),  256, 0, stream>>>(hb16, nu_log, theta_log, 0, 1);

    gemm_mfma<false><<<2048, 256, 0, stream>>>(hb16, C16, nullptr, out, ROWS);
}

// Round 4
// 398.423 us; speedup vs baseline: 1.1533x; 1.1533x over previous
//
#include <hip/hip_runtime.h>

// TreeLRU: B=16, N=4095 heap, IN=OUT=512, S=256.
// Round 8: round-7's depth-3 counted-vmcnt pipeline REGRESSED (85->120us):
// 2x barrier count, stage on critical path, 64B-segment reads. Reverted to
// the round-6 inner structure (known 85us) and made the GEMM PERSISTENT:
// 512 blocks (2/CU, one generation), each block owns one 128-col panel
// (B L2-hot) and sweeps 4 row-tiles with a seamless 32-iteration pipeline
// (cross-tile prefetch at it=7; epilogue stores overlap next tile's
// first-K flight). Amortizes per-block prologue/epilogue/ramp 4x.
// prep_all / tree_up2 unchanged (attribution).

#define ROWS 65520
#define KDIM 512

typedef __attribute__((ext_vector_type(8))) short bf16x8;
typedef __attribute__((ext_vector_type(4))) float f32x4;

__device__ __forceinline__ unsigned short f2bf(float f) {
    unsigned int u = __float_as_uint(f);
    unsigned int r = (u + 0x7FFFu + ((u >> 16) & 1u)) >> 16;
    return (unsigned short)r;
}
__device__ __forceinline__ float b2f(unsigned short h) {
    return __uint_as_float(((unsigned int)h) << 16);
}
__device__ __forceinline__ float b2f_lo(unsigned int p) {      // low bf16 of pair
    return __uint_as_float(p << 16);
}
__device__ __forceinline__ float b2f_hi(unsigned int p) {      // high bf16 of pair
    return __uint_as_float(p & 0xFFFF0000u);
}

// ---------------- merged prep: prep_M | prep_C | prep_bias | cvt ----------------
#define PC_BASE   1024
#define PB_BASE   2048
#define CVT_BASE  2176
#define CVT_BLKS  2048
#define PREP_GRID 4224
#define CVT_N4    8386560          // ROWS*512/4

__global__ __launch_bounds__(256) void prep_all(const float* __restrict__ x,
                                                unsigned short* __restrict__ x16,
                                                const float* __restrict__ W,
                                                const float* __restrict__ Bre,
                                                const float* __restrict__ Bim,
                                                const float* __restrict__ gamma_log,
                                                unsigned short* __restrict__ M16,
                                                const float* __restrict__ bin,
                                                float* __restrict__ biasc,
                                                const float* __restrict__ Cre,
                                                const float* __restrict__ Cim,
                                                unsigned short* __restrict__ C16) {
    __shared__ float Bs[16][17];
    __shared__ float Ws[16][17];
    const int blk = blockIdx.x;
    const int t = threadIdx.x;

    if (blk < PC_BASE) {
        // ---- prep_M: 32x32 grid of 16x16 tiles ----
        const int bx = blk & 31;       // j tile
        const int by = blk >> 5;       // cc tile
        const int tx = t & 15;
        const int ty = t >> 4;
        const int j  = bx * 16 + tx;
        const int cc = by * 16 + ty;
        const float* Bsel = (cc < 256) ? (Bre + (size_t)cc * 512)
                                       : (Bim + (size_t)(cc - 256) * 512);
        float acc = 0.f;
        for (int kt = 0; kt < 512; kt += 16) {
            Bs[ty][tx] = Bsel[kt + tx];
            Ws[ty][tx] = W[(size_t)(kt + ty) * 512 + j];
            __syncthreads();
#pragma unroll
            for (int k = 0; k < 16; ++k) acc += Bs[ty][k] * Ws[k][tx];
            __syncthreads();
        }
        float g = expf(gamma_log[cc & 255]);
        M16[(size_t)cc * 512 + j] = f2bf(acc * g);
    } else if (blk < PB_BASE) {
        // ---- prep_C ----
        int idx = (blk - PC_BASE) * 256 + t;   // 0..262143
        int o = idx >> 9;
        int s = idx & 511;
        float v = (s < 256) ? Cre[(size_t)o * 256 + s] : -Cim[(size_t)o * 256 + (s - 256)];
        C16[idx] = f2bf(v);
    } else if (blk < CVT_BASE) {
        // ---- prep_bias: 4 channels per block, one wave each ----
        const int c = (blk - PB_BASE) * 4 + (t >> 6);   // 0..511
        const int lane = t & 63;
        const float* Bsel = (c < 256) ? (Bre + (size_t)c * 512)
                                      : (Bim + (size_t)(c - 256) * 512);
        float acc = 0.f;
#pragma unroll
        for (int i = lane; i < 512; i += 64) acc += bin[i] * Bsel[i];
#pragma unroll
        for (int off = 32; off > 0; off >>= 1) acc += __shfl_down(acc, off, 64);
        if (lane == 0) biasc[c] = acc * expf(gamma_log[c & 255]);
    } else {
        // ---- cvt f32 -> bf16, grid-stride: 16 float4 per thread ----
        int i = (blk - CVT_BASE) * 256 + t;
#pragma unroll 4
        for (; i < CVT_N4; i += CVT_BLKS * 256) {
            float4 v = ((const float4*)x)[i];
            ushort4 o;
            o.x = f2bf(v.x); o.y = f2bf(v.y); o.z = f2bf(v.z); o.w = f2bf(v.w);
            ((ushort4*)x16)[i] = o;
        }
    }
}

// ---------------- bf16 MFMA GEMM: C = A @ B^T (+bias), K=N=512 ----------------
// Persistent: 512 blocks; block p: xcd=p&7, q=p>>3, colblk=q&3, rg=q>>2.
// Sweeps 4 row-tiles: rowblk(j) = xcd*64 + rg*4 + j. The 4 colblk-siblings
// (same xcd, same rg) hit the SAME rowblk at the same time j -> A panel
// L2-shared; each block's B panel (128KB) stays L2-hot across tiles.
// Inner structure = round 6: 128x128 tile, 4 waves, BK=64, 2 LDS buffers,
// STAGE(next) at iter top, __syncthreads (vmcnt0 drain) at iter bottom.
// Cross-tile: at it=7 stage tile j+1's K-tile 0; epilogue stores of tile j
// run while that prefetch is in flight. acc reset per tile; no pipe drain.
template <bool OUT_BF16>
__global__ __launch_bounds__(256) void gemm_mfma(const unsigned short* __restrict__ A,
                                                 const unsigned short* __restrict__ Bm,
                                                 const float* __restrict__ bias,
                                                 void* __restrict__ Cout,
                                                 int Mrows) {
    __shared__ __align__(16) unsigned short As[2][128 * 64];
    __shared__ __align__(16) unsigned short Bs[2][128 * 64];
    const int t = threadIdx.x;
    const int lane = t & 63;
    const int w = t >> 6;
    const int wr = (w >> 1) * 64;
    const int wc = (w & 1) * 64;
    const int p = blockIdx.x;               // 0..511
    const int xcd = p & 7;
    const int q = p >> 3;                   // 0..63
    const int colblk = q & 3;
    const int rg = q >> 2;                  // 0..15
    const int col0 = colblk * 128;

    // per-thread stage geometry (tile-invariant pieces)
    int arow[4], akoff[4], ldsoff[4];
    const unsigned short* gbB[4];
#pragma unroll
    for (int qq = 0; qq < 4; ++qq) {
        int c_   = qq * 256 + t;           // chunk id 0..1023
        int row_ = c_ >> 3;
        int kc_  = c_ & 7;
        int kg_  = kc_ ^ (row_ & 7);
        arow[qq]  = row_;
        akoff[qq] = kg_ * 8;
        ldsoff[qq] = c_ * 8;
        gbB[qq] = Bm + (size_t)(col0 + row_) * KDIM + kg_ * 8;
    }
    const unsigned short* gaB[4];

    // set A stage bases for tile j
#define SET_TILE_A(ROW0)                                                       \
    do {                                                                       \
        _Pragma("unroll")                                                      \
        for (int qq = 0; qq < 4; ++qq) {                                       \
            int ar_ = (ROW0) + arow[qq]; if (ar_ >= Mrows) ar_ = Mrows - 1;    \
            gaB[qq] = A + (size_t)ar_ * KDIM + akoff[qq];                      \
        }                                                                      \
    } while (0)

#define STAGE(pb, KT)                                                          \
    do {                                                                       \
        _Pragma("unroll")                                                      \
        for (int qq = 0; qq < 4; ++qq) {                                       \
            __builtin_amdgcn_global_load_lds(                                  \
                (const __attribute__((address_space(1))) unsigned int*)(gaB[qq] + (KT)), \
                (__attribute__((address_space(3))) unsigned int*)(&As[pb][ldsoff[qq]]), \
                16, 0, 0);                                                     \
            __builtin_amdgcn_global_load_lds(                                  \
                (const __attribute__((address_space(1))) unsigned int*)(gbB[qq] + (KT)), \
                (__attribute__((address_space(3))) unsigned int*)(&Bs[pb][ldsoff[qq]]), \
                16, 0, 0);                                                     \
        }                                                                      \
    } while (0)

    f32x4 acc[4][4] = {};

    int rowblk = xcd * 64 + rg * 4;        // tile j=0
    int row0 = rowblk * 128;
    int kt0 = (rowblk & 7) * 64;
    SET_TILE_A(row0);
    STAGE(0, kt0);
    __syncthreads();                        // tile0 K0 resident

    int cur = 0;
    for (int j = 0; j < 4; ++j) {
        // tile j: row0/kt0/gaB already set
        for (int it = 0; it < 8; ++it) {
            if (it < 7) {
                STAGE(cur ^ 1, (kt0 + (it + 1) * 64) & 511);
            } else if (j < 3) {
                // cross-tile prefetch: tile j+1, its K-tile 0
                const int nrowblk = rowblk + 1;
                SET_TILE_A(nrowblk * 128);
                STAGE(cur ^ 1, (nrowblk & 7) * 64);
            }
            __builtin_amdgcn_s_setprio(1);
#pragma unroll
            for (int kk = 0; kk < 64; kk += 32) {
                const int kgc = kk >> 3;  // 0 or 4
                bf16x8 af[4], bfr[4];
#pragma unroll
                for (int i = 0; i < 4; ++i) {
                    int row = wr + i * 16 + (lane & 15);
                    int kca = (kgc + (lane >> 4)) ^ (row & 7);
                    af[i] = *(const bf16x8*)(&As[cur][row * 64 + kca * 8]);
                    int colr = wc + i * 16 + (lane & 15);
                    int kcb = (kgc + (lane >> 4)) ^ (colr & 7);
                    bfr[i] = *(const bf16x8*)(&Bs[cur][colr * 64 + kcb * 8]);
                }
#pragma unroll
                for (int i = 0; i < 4; ++i)
#pragma unroll
                    for (int jj = 0; jj < 4; ++jj)
                        acc[i][jj] = __builtin_amdgcn_mfma_f32_16x16x32_bf16(
                            af[i], bfr[jj], acc[i][jj], 0, 0, 0);
            }
            __builtin_amdgcn_s_setprio(0);
            __syncthreads();    // publishes prefetched tile
            cur ^= 1;
        }

        // epilogue for tile j (overlaps flight of tile j+1's K0)
        const int cq = lane >> 4;
        const int cl = lane & 15;
#pragma unroll
        for (int i = 0; i < 4; ++i) {
#pragma unroll
            for (int jj = 0; jj < 4; ++jj) {
#pragma unroll
                for (int r = 0; r < 4; ++r) {
                    int grow = row0 + wr + i * 16 + cq * 4 + r;
                    int gcol = col0 + wc + jj * 16 + cl;
                    if (grow < Mrows) {
                        float v = acc[i][jj][r];
                        if (bias) v += bias[gcol];
                        if (OUT_BF16)
                            ((unsigned short*)Cout)[(size_t)grow * 512 + gcol] = f2bf(v);
                        else
                            ((float*)Cout)[(size_t)grow * 512 + gcol] = v;
                    }
                    acc[i][jj][r] = 0.f;
                }
            }
        }

        // advance tile bookkeeping (gaB already points at tile j+1)
        rowblk += 1;
        row0 = rowblk * 128;
        kt0 = (rowblk & 7) * 64;
    }
#undef STAGE
#undef SET_TILE_A
}

// ---------------- tree recurrence, v2 (unchanged) ----------------
template <int E>
__global__ __launch_bounds__(256) void tree_up2(unsigned short* __restrict__ buf,
                                                const float* __restrict__ nu_log,
                                                const float* __restrict__ theta_log,
                                                int root_base, int nroots) {
    const int b = blockIdx.x;
    const int h = threadIdx.x >> 7;
    const int j2 = (threadIdx.x & 127) * 2;        // channel pair base
    const int rr = blockIdx.y * 2 + h;
    if (rr >= nroots) return;
    const int rs = root_base + rr;
    constexpr int LEAVES = 1 << E;
    constexpr int NODES = LEAVES - 1;

    float lr0, li0, lr1, li1;
    { const float lam = expf(-expf(nu_log[j2]));     const float th = expf(theta_log[j2]);
      lr0 = lam * cosf(th); li0 = lam * sinf(th); }
    { const float lam = expf(-expf(nu_log[j2 + 1])); const float th = expf(theta_log[j2 + 1]);
      lr1 = lam * cosf(th); li1 = lam * sinf(th); }
    const size_t base = (size_t)b * 4095;

    // 1) issue ALL loads (62 x 4B per thread, independent) ...
    unsigned int pr[LEAVES], pi[LEAVES];
    const int nbL = ((rs + 1) << E) - 1;
#pragma unroll
    for (int i = 0; i < LEAVES; ++i) {
        const size_t r = (base + nbL + i) * 512;
        pr[i] = *(const unsigned int*)(buf + r + j2);
        pi[i] = *(const unsigned int*)(buf + r + 256 + j2);
    }
    unsigned int qr[NODES], qi[NODES];
#pragma unroll
    for (int e = E - 1; e >= 0; --e) {
#pragma unroll
        for (int i = 0; i < (1 << e); ++i) {
            const int idx = LEAVES - (2 << e) + i;
            const size_t r = (base + (((rs + 1) << e) - 1) + i) * 512;
            qr[idx] = *(const unsigned int*)(buf + r + j2);
            qi[idx] = *(const unsigned int*)(buf + r + 256 + j2);
        }
    }
    // ... 2) and only then start consuming (pins MLP; prevents load sinking)
    __builtin_amdgcn_sched_barrier(0);

    float vr0[LEAVES], vi0[LEAVES], vr1[LEAVES], vi1[LEAVES];
#pragma unroll
    for (int i = 0; i < LEAVES; ++i) {
        vr0[i] = b2f_lo(pr[i]); vr1[i] = b2f_hi(pr[i]);
        vi0[i] = b2f_lo(pi[i]); vi1[i] = b2f_hi(pi[i]);
    }
#pragma unroll
    for (int e = E - 1; e >= 0; --e) {
#pragma unroll
        for (int i = 0; i < (1 << e); ++i) {
            const int idx = LEAVES - (2 << e) + i;
            const float cr0 = vr0[2 * i] + vr0[2 * i + 1];
            const float ci0 = vi0[2 * i] + vi0[2 * i + 1];
            const float cr1 = vr1[2 * i] + vr1[2 * i + 1];
            const float ci1 = vi1[2 * i] + vi1[2 * i + 1];
            const float hr0 = lr0 * cr0 - li0 * ci0 + b2f_lo(qr[idx]);
            const float hi0 = lr0 * ci0 + li0 * cr0 + b2f_lo(qi[idx]);
            const float hr1 = lr1 * cr1 - li1 * ci1 + b2f_hi(qr[idx]);
            const float hi1 = lr1 * ci1 + li1 * cr1 + b2f_hi(qi[idx]);
            const size_t r = (base + (((rs + 1) << e) - 1) + i) * 512;
            *(unsigned int*)(buf + r + j2) =
                (unsigned int)f2bf(hr0) | ((unsigned int)f2bf(hr1) << 16);
            *(unsigned int*)(buf + r + 256 + j2) =
                (unsigned int)f2bf(hi0) | ((unsigned int)f2bf(hi1) << 16);
            vr0[i] = hr0; vi0[i] = hi0; vr1[i] = hr1; vi1[i] = hi1;
        }
    }
}

extern "C" void kernel_launch(void* const* d_in, const int* in_sizes, int n_in,
                              void* d_out, int out_size, void* d_ws, size_t ws_size,
                              hipStream_t stream) {
    const float* x         = (const float*)d_in[0];
    const float* W_in      = (const float*)d_in[2];
    const float* b_in      = (const float*)d_in[3];
    const float* nu_log    = (const float*)d_in[4];
    const float* theta_log = (const float*)d_in[5];
    const float* gamma_log = (const float*)d_in[6];
    const float* B_re      = (const float*)d_in[7];
    const float* B_im      = (const float*)d_in[8];
    const float* C_re      = (const float*)d_in[9];
    const float* C_im      = (const float*)d_in[10];
    float* out = (float*)d_out;

    char* ws = (char*)d_ws;
    const size_t HB = (size_t)ROWS * 512 * 2;   // 67,092,480 bytes
    unsigned short* x16   = (unsigned short*)ws;
    unsigned short* hb16  = (unsigned short*)(ws + HB);
    unsigned short* M16   = (unsigned short*)(ws + 2 * HB);
    unsigned short* C16   = (unsigned short*)(ws + 2 * HB + 512 * 512 * 2);
    float*          biasc = (float*)(ws + 2 * HB + 2 * 512 * 512 * 2);

    prep_all<<<PREP_GRID, 256, 0, stream>>>(x, x16, W_in, B_re, B_im, gamma_log,
                                            M16, b_in, biasc, C_re, C_im, C16);

    gemm_mfma<true><<<512, 256, 0, stream>>>(x16, M16, biasc, hb16, ROWS);

    // levels 10..7 (roots at level 7: nodes 127..254), then 6..3 (roots at
    // level 3: nodes 7..14), then 2..0 (root 0).
    tree_up2<4><<<dim3(16, 64), 256, 0, stream>>>(hb16, nu_log, theta_log, 127, 128);
    tree_up2<4><<<dim3(16, 4),  256, 0, stream>>>(hb16, nu_log, theta_log, 7, 8);
    tree_up2<3><<<dim3(16, 1),  256, 0, stream>>>(hb16, nu_log, theta_log, 0, 1);

    gemm_mfma<false><<<512, 256, 0, stream>>>(hb16, C16, nullptr, out, ROWS);
}